// Round 12
// baseline (525.066 us; speedup 1.0000x reference)
//
#include <hip/hip_runtime.h>
#include <math.h>

#define ENH_PAD 160   // 144 padded to multiple of 32 for MFMA K-loop
#define POSD 16

typedef __attribute__((ext_vector_type(8))) __bf16 bf16x8;
typedef __attribute__((ext_vector_type(4))) float f32x4;

__device__ __forceinline__ unsigned short f2bf(float f){
  unsigned int u = __float_as_uint(f);
  u += 0x7FFF + ((u >> 16) & 1);          // round-to-nearest-even
  return (unsigned short)(u >> 16);
}
__device__ __forceinline__ float bf2f(unsigned short u){
  return __uint_as_float(((unsigned int)u) << 16);
}

// ---- fused front: starts + in-degree + zero bnstats/pooled + weight pack ----
__global__ void k_front(const int* __restrict__ batch, int* __restrict__ starts,
                        const int* __restrict__ dst, int* __restrict__ indeg,
                        float* __restrict__ bnstats, float* __restrict__ pooled,
                        const float* __restrict__ W1, const float* __restrict__ W2,
                        unsigned short* __restrict__ W1t, unsigned short* __restrict__ W2t,
                        int N, int E, int EB){
  if ((int)blockIdx.x >= EB){
    // weight packing blocks
    int idx = (blockIdx.x - EB) * 256 + threadIdx.x;
    const int n1 = 256 * ENH_PAD;
    if (idx < n1){
      int n = idx / ENH_PAD, k = idx - n * ENH_PAD;
      W1t[idx] = f2bf((k < 144) ? W1[(size_t)k * 256 + n] : 0.f);
    } else {
      int j = idx - n1;
      if (j < 256 * 256){
        int n = j >> 8, k = j & 255;
        W2t[j] = f2bf(W2[(size_t)k * 256 + n]);
      }
    }
    return;
  }
  int i = blockIdx.x * blockDim.x + threadIdx.x;
  if (i < 1024) bnstats[i] = 0.f;
  if (i < 64 * 256) pooled[i] = 0.f;
  if (i < N){
    int bi = batch[i];
    int bp = (i == 0) ? -1 : batch[i - 1];
    for (int b = bp + 1; b <= bi; ++b) starts[b] = i;
    if (i == N - 1){
      for (int b = bi + 1; b <= 64; ++b) starts[b] = N;
    }
  }
  if (i < E) atomicAdd(&indeg[dst[i]], 1);
}

// ---- h0 (bf16, K padded to 160): 4 nodes per block --------------------------
__global__ __launch_bounds__(256) void k_build_h0(
    const float* __restrict__ x, const int* __restrict__ batch,
    const int* __restrict__ starts, const int* __restrict__ gsize,
    const float* __restrict__ invden,
    const float* __restrict__ W_pos, const float* __restrict__ b_pos,
    unsigned short* __restrict__ h0, int N){
  int n = blockIdx.x * 4 + (threadIdx.x >> 6);
  if (n >= N) return;
  int t = threadIdx.x & 63;
  unsigned short* hrow = h0 + (size_t)n * ENH_PAD;
  if (t < 32){
    const float4* xs = (const float4*)(x + (size_t)n * 128);
    float4 v = xs[t];
    ushort4 o; o.x = f2bf(v.x); o.y = f2bf(v.y); o.z = f2bf(v.z); o.w = f2bf(v.w);
    ((ushort4*)hrow)[t] = o;
  } else if (t < 48){
    int k = t - 32;
    int b = batch[n];
    int i = n - starts[b];
    int g = gsize[b];
    int row = i / g;
    int col = i - row * g;
    float idn = invden[b];
    float pe = (float)row * idn * W_pos[k] + (float)col * idn * W_pos[POSD + k] + b_pos[k];
    hrow[128 + k] = f2bf(pe);
  } else {
    hrow[144 + (t - 48)] = 0;     // zero pad cols 144..159
  }
}

// ---- bf16 MFMA GEMM + fused attention logits --------------------------------
#define LDST 40   // LDS row stride in bf16 (2-way bank aliasing, free)
__global__ __launch_bounds__(256) void k_mfma_gemm(
    const unsigned short* __restrict__ A, const unsigned short* __restrict__ Bt,
    unsigned short* __restrict__ C,
    const float* __restrict__ a_src, const float* __restrict__ a_dst,
    float* __restrict__ alpS, float* __restrict__ alpD, int M, int Kp){
  __shared__ unsigned short As[128 * LDST];
  __shared__ unsigned short Bs[128 * LDST];
  int t = threadIdx.x;
  int lane = t & 63, wave = t >> 6;
  int wm = (wave >> 1) * 64, wn = (wave & 1) * 64;
  int quad = lane >> 4, l16 = lane & 15;
  int row0 = blockIdx.x * 128;
  int n0 = blockIdx.y * 128;

  f32x4 acc[4][4] = {};

  int eA0 = t, eA1 = t + 256;
  for (int kk = 0; kk < Kp; kk += 32){
    #pragma unroll
    for (int rep = 0; rep < 2; ++rep){
      int e = rep ? eA1 : eA0;
      int r = e >> 2, s = e & 3;
      int grow = row0 + r;
      uint4 va = make_uint4(0, 0, 0, 0);
      if (grow < M) va = *(const uint4*)(A + (size_t)grow * Kp + kk + s * 8);
      *(uint4*)&As[r * LDST + s * 8] = va;
      uint4 vb = *(const uint4*)(Bt + (size_t)(n0 + r) * Kp + kk + s * 8);
      *(uint4*)&Bs[r * LDST + s * 8] = vb;
    }
    __syncthreads();
    bf16x8 af[4], bfr[4];
    #pragma unroll
    for (int i = 0; i < 4; ++i)
      af[i] = *(const bf16x8*)&As[(wm + i * 16 + l16) * LDST + quad * 8];
    #pragma unroll
    for (int j = 0; j < 4; ++j)
      bfr[j] = *(const bf16x8*)&Bs[(wn + j * 16 + l16) * LDST + quad * 8];
    #pragma unroll
    for (int i = 0; i < 4; ++i)
      #pragma unroll
      for (int j = 0; j < 4; ++j)
        acc[i][j] = __builtin_amdgcn_mfma_f32_16x16x32_bf16(af[i], bfr[j], acc[i][j], 0, 0, 0);
    __syncthreads();
  }
  // C store: C/D layout col=lane&15, row=quad*4+reg
  #pragma unroll
  for (int i = 0; i < 4; ++i){
    int rbase = row0 + wm + i * 16 + quad * 4;
    #pragma unroll
    for (int j = 0; j < 4; ++j){
      int col = n0 + wn + j * 16 + l16;
      #pragma unroll
      for (int r = 0; r < 4; ++r){
        int row = rbase + r;
        if (row < M) C[(size_t)row * 256 + col] = f2bf(acc[i][j][r]);
      }
    }
  }
  // fused alphas: this wave's columns n0+wn..+63 == head hda
  int hda = (n0 + wn) >> 6;
  float asw[4], adw[4];
  #pragma unroll
  for (int j = 0; j < 4; ++j){
    int c = n0 + wn + j * 16 + l16;
    asw[j] = a_src[c];
    adw[j] = a_dst[c];
  }
  #pragma unroll
  for (int i = 0; i < 4; ++i){
    #pragma unroll
    for (int r = 0; r < 4; ++r){
      int row = row0 + wm + i * 16 + quad * 4 + r;
      float ps = acc[i][0][r] * asw[0] + acc[i][1][r] * asw[1]
               + acc[i][2][r] * asw[2] + acc[i][3][r] * asw[3];
      float pd = acc[i][0][r] * adw[0] + acc[i][1][r] * adw[1]
               + acc[i][2][r] * adw[2] + acc[i][3][r] * adw[3];
      ps += __shfl_xor(ps, 1); ps += __shfl_xor(ps, 2);
      ps += __shfl_xor(ps, 4); ps += __shfl_xor(ps, 8);
      pd += __shfl_xor(pd, 1); pd += __shfl_xor(pd, 2);
      pd += __shfl_xor(pd, 4); pd += __shfl_xor(pd, 8);
      if (l16 == 0 && row < M){
        alpS[row * 4 + hda] = ps;
        alpD[row * 4 + hda] = pd;
      }
    }
  }
}

// ---- parallel scan of indeg -> row_ptr / cursor -----------------------------
__device__ __forceinline__ int block_excl_scan_256(int val, int* lds){
  int t = threadIdx.x;
  int lane = t & 63, w = t >> 6;
  int incl = val;
  #pragma unroll
  for (int off = 1; off < 64; off <<= 1){
    int v = __shfl_up(incl, off);
    if (lane >= off) incl += v;
  }
  if (lane == 63) lds[w] = incl;
  __syncthreads();
  int wofs = 0;
  #pragma unroll
  for (int i = 0; i < 4; ++i) if (i < w) wofs += lds[i];
  return wofs + incl - val;
}

__global__ __launch_bounds__(256) void k_scan1(const int* __restrict__ indeg,
                                               int* __restrict__ bsums, int N){
  int i = blockIdx.x * 256 + threadIdx.x;
  int v = (i < N) ? indeg[i] : 0;
  int s = v;
  #pragma unroll
  for (int off = 32; off; off >>= 1) s += __shfl_xor(s, off);
  __shared__ int wt[4];
  if ((threadIdx.x & 63) == 0) wt[threadIdx.x >> 6] = s;
  __syncthreads();
  if (threadIdx.x == 0) bsums[blockIdx.x] = wt[0] + wt[1] + wt[2] + wt[3];
}

__global__ __launch_bounds__(1024) void k_scan2_meta(const int* __restrict__ bsums,
                                                     int* __restrict__ boffs,
                                                     int* __restrict__ row_ptr,
                                                     const int* __restrict__ starts,
                                                     int* __restrict__ gsize,
                                                     float* __restrict__ invden,
                                                     float* __restrict__ invcnt,
                                                     int NB, int N){
  int t = threadIdx.x;
  if (t < 64){
    int c = starts[t + 1] - starts[t];
    int g = (int)ceilf(sqrtf((float)c));
    gsize[t] = g;
    int dd = g - 1; if (dd < 1) dd = 1;
    invden[t] = 1.0f / (float)dd;
    invcnt[t] = (c > 0) ? 1.0f / (float)c : 0.0f;
  }
  int v = (t < NB) ? bsums[t] : 0;
  int lane = t & 63, w = t >> 6;
  int incl = v;
  #pragma unroll
  for (int off = 1; off < 64; off <<= 1){
    int x = __shfl_up(incl, off);
    if (lane >= off) incl += x;
  }
  __shared__ int wt[16];
  if (lane == 63) wt[w] = incl;
  __syncthreads();
  int wofs = 0;
  for (int i = 0; i < w; ++i) wofs += wt[i];
  if (t < NB) boffs[t] = wofs + incl - v;
  if (t == 1023){
    int tot = 0;
    for (int i = 0; i < 16; ++i) tot += wt[i];
    row_ptr[N] = tot;
  }
}

__global__ __launch_bounds__(256) void k_scan3(const int* __restrict__ indeg,
                                               const int* __restrict__ boffs,
                                               int* __restrict__ row_ptr,
                                               int* __restrict__ cursor, int N){
  __shared__ int lds[4];
  int i = blockIdx.x * 256 + threadIdx.x;
  int v = (i < N) ? indeg[i] : 0;
  int ex = block_excl_scan_256(v, lds) + boffs[blockIdx.x];
  if (i < N){
    row_ptr[i] = ex;
    cursor[i] = ex;
  }
}

__global__ void k_scatter(const int* __restrict__ src, const int* __restrict__ dst,
                          int* cursor, int* __restrict__ csr_src, int E){
  int e = blockIdx.x * blockDim.x + threadIdx.x;
  if (e < E){
    int slot = atomicAdd(&cursor[dst[e]], 1);
    csr_src[slot] = src[e];
  }
}

// ---- GAT aggregation: one wave/node, 4 heads.
//      Fast path (total <= 32, ~99.98% of nodes): scores for all 32 slots
//      upfront, then ALL gathers issued (4-granular wave-uniform groups,
//      scalar-indexed), then accumulate — one flat latency chain.
//      Slow path: 16-chunk loop for edges past 32. --------------------------
__global__ __launch_bounds__(256) void k_aggregate(const unsigned short* __restrict__ hlin,
                                                   const float* __restrict__ alpS,
                                                   const float* __restrict__ alpD,
                                                   const int* __restrict__ row_ptr,
                                                   const int* __restrict__ csr_src,
                                                   const float* __restrict__ bias,
                                                   unsigned short* __restrict__ outb, int N){
  int n = blockIdx.x * 4 + (threadIdx.x >> 6);
  if (n >= N) return;
  int lane = threadIdx.x & 63;
  int hd = lane >> 4;          // channel-domain head
  int hd2 = lane & 3;          // score-domain head
  int eloc = lane >> 2;        // score-domain edge slot 0..15
  int beg = __builtin_amdgcn_readfirstlane(row_ptr[n]);
  int deg = __builtin_amdgcn_readfirstlane(row_ptr[n + 1]) - beg;
  int ns  = __builtin_amdgcn_readfirstlane(n);
  int total = deg + 1;         // + implicit self-loop
  float ad2 = alpD[n * 4 + hd2];
  float lsum = 0.f;
  float a0 = 0.f, a1 = 0.f, a2 = 0.f, a3 = 0.f;
  const unsigned short* hbase = hlin + (size_t)lane * 4;

  // ---- fast path: first min(total,32) edges, flat ----
  int e1 = eloc, e2 = 16 + eloc;
  int sv1 = (e1 < deg) ? csr_src[beg + e1] : n;
  int sv2 = (e2 < deg) ? csr_src[beg + e2] : n;
  float p1 = 0.f, p2 = 0.f;
  if (e1 < total){
    float xv = alpS[sv1 * 4 + hd2] + ad2;
    float sc = (xv >= 0.f) ? xv : 0.2f * xv;
    p1 = __expf(sc);
  }
  if (e2 < total){
    float xv = alpS[sv2 * 4 + hd2] + ad2;
    float sc = (xv >= 0.f) ? xv : 0.2f * xv;
    p2 = __expf(sc);
  }
  lsum = p1 + p2;

  int tcap = min(total, 32);
  int ng = (tcap + 3) >> 2;               // 1..8 groups of 4 (wave-uniform)
  uint2 v[8][4];
  #pragma unroll
  for (int g = 0; g < 8; ++g){
    if (g < ng){
      #pragma unroll
      for (int q = 0; q < 4; ++q){
        int idx = g * 4 + q;              // scalar
        int sj = (idx < deg) ? csr_src[beg + idx] : ns;
        v[g][q] = *(const uint2*)(hbase + (size_t)sj * 256);
      }
    }
  }
  #pragma unroll
  for (int g = 0; g < 8; ++g){
    if (g < ng){
      #pragma unroll
      for (int q = 0; q < 4; ++q){
        int j2 = g * 4 + q;
        float pj = (j2 < 16) ? __shfl(p1, (j2 << 2) | hd)
                             : __shfl(p2, ((j2 - 16) << 2) | hd);
        a0 += pj * __uint_as_float(v[g][q].x << 16);
        a1 += pj * __uint_as_float(v[g][q].x & 0xFFFF0000u);
        a2 += pj * __uint_as_float(v[g][q].y << 16);
        a3 += pj * __uint_as_float(v[g][q].y & 0xFFFF0000u);
      }
    }
  }

  // ---- slow path: edges 32.. (rare) ----
  if (total > 32){
    int base = 32;
    for (; base + 16 <= total; base += 16){
      int e = base + eloc;
      int sv = (e < deg) ? csr_src[beg + e] : n;
      float xv = alpS[sv * 4 + hd2] + ad2;
      float sc = (xv >= 0.f) ? xv : 0.2f * xv;
      float p = __expf(sc);
      lsum += p;
      uint2 vv[16];
      #pragma unroll
      for (int j2 = 0; j2 < 16; ++j2){
        int idx = base + j2;              // scalar
        int sj = (idx < deg) ? csr_src[beg + idx] : ns;
        vv[j2] = *(const uint2*)(hbase + (size_t)sj * 256);
      }
      #pragma unroll
      for (int j2 = 0; j2 < 16; ++j2){
        float pj = __shfl(p, (j2 << 2) | hd);
        a0 += pj * __uint_as_float(vv[j2].x << 16);
        a1 += pj * __uint_as_float(vv[j2].x & 0xFFFF0000u);
        a2 += pj * __uint_as_float(vv[j2].y << 16);
        a3 += pj * __uint_as_float(vv[j2].y & 0xFFFF0000u);
      }
    }
    int rem = total - base;               // 0..15
    if (rem){
      int e = base + eloc;
      int s = n;
      float p = 0.f;
      if (eloc < rem){
        if (e < deg) s = csr_src[beg + e];
        float xv = alpS[s * 4 + hd2] + ad2;
        float sc = (xv >= 0.f) ? xv : 0.2f * xv;
        p = __expf(sc);
      }
      lsum += p;
      #pragma unroll
      for (int g = 0; g < 4; ++g){
        if (g * 4 < rem){                 // wave-uniform
          uint2 vv[4];
          #pragma unroll
          for (int q = 0; q < 4; ++q){
            int idx = base + g * 4 + q;   // scalar
            int sj = (idx < deg) ? csr_src[beg + idx] : ns;
            vv[q] = *(const uint2*)(hbase + (size_t)sj * 256);
          }
          #pragma unroll
          for (int q = 0; q < 4; ++q){
            int j2 = g * 4 + q;
            float pj = __shfl(p, (j2 << 2) | hd);
            a0 += pj * __uint_as_float(vv[q].x << 16);
            a1 += pj * __uint_as_float(vv[q].x & 0xFFFF0000u);
            a2 += pj * __uint_as_float(vv[q].y << 16);
            a3 += pj * __uint_as_float(vv[q].y & 0xFFFF0000u);
          }
        }
      }
    }
  }

  lsum += __shfl_xor(lsum, 4);
  lsum += __shfl_xor(lsum, 8);
  lsum += __shfl_xor(lsum, 16);
  lsum += __shfl_xor(lsum, 32);
  float lh = __shfl(lsum, hd);
  float inv = 1.0f / lh;
  float4 bv = *(const float4*)(bias + lane * 4);
  ushort4 o;
  o.x = f2bf(a0 * inv + bv.x);
  o.y = f2bf(a1 * inv + bv.y);
  o.z = f2bf(a2 * inv + bv.z);
  o.w = f2bf(a3 * inv + bv.w);
  *(ushort4*)(outb + (size_t)n * 256 + lane * 4) = o;
}

// ---- BatchNorm stats (bf16 input) -------------------------------------------
__global__ __launch_bounds__(256) void k_bn_stats(const unsigned short* __restrict__ in,
                                                  float* __restrict__ sums,
                                                  float* __restrict__ sqs, int N){
  int t = threadIdx.x;
  int nb = gridDim.x;
  int rows = (N + nb - 1) / nb;
  int r0 = blockIdx.x * rows, r1 = min(r0 + rows, N);
  float s = 0.f, q = 0.f;
  for (int r = r0; r < r1; ++r){
    float v = bf2f(in[(size_t)r * 256 + t]);
    s += v; q += v * v;
  }
  atomicAdd(&sums[t], s);
  atomicAdd(&sqs[t], q);
}

// ---- BN apply + ELU (bf16 in -> bf16 out, layer 1) --------------------------
__global__ void k_bn_elu_bf16(const unsigned short* __restrict__ in,
                              const float* __restrict__ sums,
                              const float* __restrict__ sqs, const float* __restrict__ gamma,
                              const float* __restrict__ beta,
                              unsigned short* __restrict__ outb, int N, float invN){
  int idx = blockIdx.x * blockDim.x + threadIdx.x;
  int total = N * 256;
  for (; idx < total; idx += gridDim.x * blockDim.x){
    int c = idx & 255;
    float mean = sums[c] * invN;
    float var = sqs[c] * invN - mean * mean;
    float inv = rsqrtf(var + 1e-5f);
    float y = gamma[c] * (bf2f(in[idx]) - mean) * inv + beta[c];
    y = (y > 0.f) ? y : (__expf(y) - 1.f);
    outb[idx] = f2bf(y);
  }
}

// ---- BN apply + ELU + mean-pool partials (bf16 in, layer 2) -----------------
__global__ __launch_bounds__(256) void k_bn_elu_pool(
    const unsigned short* __restrict__ in, const float* __restrict__ sums,
    const float* __restrict__ sqs, const float* __restrict__ gamma,
    const float* __restrict__ beta, const int* __restrict__ batch,
    float* __restrict__ pooled, int N, float invN){
  int t = threadIdx.x;
  float mean = sums[t] * invN;
  float var = sqs[t] * invN - mean * mean;
  float inv = rsqrtf(var + 1e-5f);
  float g = gamma[t], be = beta[t];
  int nb = gridDim.x;
  int rows = (N + nb - 1) / nb;
  int r0 = blockIdx.x * rows, r1 = min(r0 + rows, N);
  float acc = 0.f; int cur = -1;
  for (int r = r0; r < r1; ++r){
    float y = g * (bf2f(in[(size_t)r * 256 + t]) - mean) * inv + be;
    y = (y > 0.f) ? y : (__expf(y) - 1.f);
    int b = batch[r];
    if (b != cur){
      if (cur >= 0) atomicAdd(&pooled[cur * 256 + t], acc);
      acc = 0.f; cur = b;
    }
    acc += y;
  }
  if (cur >= 0) atomicAdd(&pooled[cur * 256 + t], acc);
}

// ---- final FC ---------------------------------------------------------------
__global__ __launch_bounds__(128) void k_final(const float* __restrict__ pooled,
                                               const float* __restrict__ invcnt,
                                               const float* __restrict__ W_fc,
                                               const float* __restrict__ b_fc,
                                               float* __restrict__ out){
  __shared__ float pm[256];
  int b = blockIdx.x;
  int t = threadIdx.x;            // 128
  float ic = invcnt[b];
  pm[t] = pooled[b * 256 + t] * ic;
  pm[t + 128] = pooled[b * 256 + t + 128] * ic;
  __syncthreads();
  float acc = b_fc[t];
  #pragma unroll 4
  for (int c = 0; c < 256; ++c) acc += pm[c] * W_fc[c * 128 + t];
  out[b * 128 + t] = acc;
}

extern "C" void kernel_launch(void* const* d_in, const int* in_sizes, int n_in,
                              void* d_out, int out_size, void* d_ws, size_t ws_size,
                              hipStream_t stream){
  const float* x      = (const float*)d_in[0];
  const int*   eidx   = (const int*)  d_in[1];
  const int*   batch  = (const int*)  d_in[2];
  const float* W_pos  = (const float*)d_in[3];
  const float* b_pos  = (const float*)d_in[4];
  const float* W1     = (const float*)d_in[5];
  const float* a_src1 = (const float*)d_in[6];
  const float* a_dst1 = (const float*)d_in[7];
  const float* b1     = (const float*)d_in[8];
  const float* gamma1 = (const float*)d_in[9];
  const float* beta1  = (const float*)d_in[10];
  const float* W2     = (const float*)d_in[11];
  const float* a_src2 = (const float*)d_in[12];
  const float* a_dst2 = (const float*)d_in[13];
  const float* b2     = (const float*)d_in[14];
  const float* gamma2 = (const float*)d_in[15];
  const float* beta2  = (const float*)d_in[16];
  const float* W_fc   = (const float*)d_in[17];
  const float* b_fc   = (const float*)d_in[18];
  float* out = (float*)d_out;

  const int N = in_sizes[0] / 128;
  const int E = in_sizes[1] / 2;
  const int* esrc = eidx;
  const int* edst = eidx + E;

  char* w = (char*)d_ws;
  size_t off = 0;
  auto alloc = [&](size_t bytes) -> void* {
    void* p = w + off;
    off = (off + bytes + 255) & ~(size_t)255;
    return p;
  };
  unsigned short* h0   = (unsigned short*)alloc((size_t)N * 256 * 2);
  unsigned short* X2b  = h0;      // reused: disjoint lifetimes (h0 dead after GEMM1)
  unsigned short* X1b  = (unsigned short*)alloc((size_t)N * 256 * 2);  // GEMM out
  unsigned short* A1b  = (unsigned short*)alloc((size_t)N * 256 * 2);  // aggregate out
  float* alpS    = (float*)alloc((size_t)N * 4 * 4);
  float* alpD    = (float*)alloc((size_t)N * 4 * 4);
  int*   starts  = (int*)  alloc(65 * 4);
  int*   gsize   = (int*)  alloc(64 * 4);
  float* invden  = (float*)alloc(64 * 4);
  float* invcnt  = (float*)alloc(64 * 4);
  int*   indeg   = (int*)  alloc((size_t)N * 4);
  int*   row_ptr = (int*)  alloc((size_t)(N + 1) * 4);
  int*   cursor  = (int*)  alloc((size_t)(N + 1) * 4);
  int*   csr_src = (int*)  alloc((size_t)(E + 32) * 4);  // +32 pad: scalar-load overrun
  int*   bsums   = (int*)  alloc(1024 * 4);
  int*   boffs   = (int*)  alloc(1024 * 4);
  float* bnstats = (float*)alloc(4 * 256 * 4);   // S1 | Q1 | S2 | Q2
  float* pooled  = (float*)alloc(64 * 256 * 4);
  unsigned short* W1t = (unsigned short*)alloc(256 * ENH_PAD * 2);
  unsigned short* W2t = (unsigned short*)alloc(256 * 256 * 2);
  float* bnS1 = bnstats, *bnQ1 = bnstats + 256, *bnS2 = bnstats + 512, *bnQ2 = bnstats + 768;

  hipMemsetAsync(indeg, 0, (size_t)N * 4, stream);

  const int NB = (N + 255) / 256;
  const int EB = (E + 255) / 256;
  const int PACKB = (256 * ENH_PAD + 256 * 256 + 255) / 256;
  int nb4 = (N + 3) / 4;

  // front-end: starts + indeg + zeroing + weight pack, then scan + scatter
  k_front<<<EB + PACKB, 256, 0, stream>>>(batch, starts, edst, indeg,
                                          bnstats, pooled, W1, W2, W1t, W2t, N, E, EB);
  k_scan1<<<NB, 256, 0, stream>>>(indeg, bsums, N);
  k_scan2_meta<<<1, 1024, 0, stream>>>(bsums, boffs, row_ptr, starts,
                                       gsize, invden, invcnt, NB, N);
  k_scan3<<<NB, 256, 0, stream>>>(indeg, boffs, row_ptr, cursor, N);
  k_scatter<<<(E + 255) / 256, 256, 0, stream>>>(esrc, edst, cursor, csr_src, E);

  k_build_h0<<<nb4, 256, 0, stream>>>(x, batch, starts, gsize, invden, W_pos, b_pos, h0, N);

  dim3 ggrid((N + 127) / 128, 2);

  // layer 1
  k_mfma_gemm<<<ggrid, 256, 0, stream>>>(h0, W1t, X1b, a_src1, a_dst1, alpS, alpD, N, ENH_PAD);
  k_aggregate<<<nb4, 256, 0, stream>>>(X1b, alpS, alpD, row_ptr, csr_src, b1, A1b, N);
  k_bn_stats<<<512, 256, 0, stream>>>(A1b, bnS1, bnQ1, N);
  k_bn_elu_bf16<<<4096, 256, 0, stream>>>(A1b, bnS1, bnQ1, gamma1, beta1, X2b, N, 1.0f / (float)N);

  // layer 2
  k_mfma_gemm<<<ggrid, 256, 0, stream>>>(X2b, W2t, X1b, a_src2, a_dst2, alpS, alpD, N, 256);
  k_aggregate<<<nb4, 256, 0, stream>>>(X1b, alpS, alpD, row_ptr, csr_src, b2, A1b, N);
  k_bn_stats<<<512, 256, 0, stream>>>(A1b, bnS2, bnQ2, N);
  k_bn_elu_pool<<<512, 256, 0, stream>>>(A1b, bnS2, bnQ2, gamma2, beta2, batch,
                                         pooled, N, 1.0f / (float)N);

  // fc
  k_final<<<64, 128, 0, stream>>>(pooled, invcnt, W_fc, b_fc, out);
}

// Round 13
// 512.530 us; speedup vs baseline: 1.0245x; 1.0245x over previous
//
#include <hip/hip_runtime.h>
#include <math.h>

#define ENH_PAD 160   // 144 padded to multiple of 32 for MFMA K-loop
#define POSD 16

typedef __attribute__((ext_vector_type(8))) __bf16 bf16x8;
typedef __attribute__((ext_vector_type(4))) float f32x4;

__device__ __forceinline__ unsigned short f2bf(float f){
  unsigned int u = __float_as_uint(f);
  u += 0x7FFF + ((u >> 16) & 1);          // round-to-nearest-even
  return (unsigned short)(u >> 16);
}
__device__ __forceinline__ float bf2f(unsigned short u){
  return __uint_as_float(((unsigned int)u) << 16);
}

// ---- fused front: starts + in-degree + zero bnstats/pooled ------------------
__global__ void k_front(const int* __restrict__ batch, int* __restrict__ starts,
                        const int* __restrict__ dst, int* __restrict__ indeg,
                        float* __restrict__ bnstats, float* __restrict__ pooled,
                        int N, int E){
  int i = blockIdx.x * blockDim.x + threadIdx.x;
  if (i < 1024) bnstats[i] = 0.f;
  if (i < 64 * 256) pooled[i] = 0.f;
  if (i < N){
    int bi = batch[i];
    int bp = (i == 0) ? -1 : batch[i - 1];
    for (int b = bp + 1; b <= bi; ++b) starts[b] = i;
    if (i == N - 1){
      for (int b = bi + 1; b <= 64; ++b) starts[b] = N;
    }
  }
  if (i < E) atomicAdd(&indeg[dst[i]], 1);
}

// ---- h0 (bf16, K padded to 160): 4 nodes per block --------------------------
__global__ __launch_bounds__(256) void k_build_h0(
    const float* __restrict__ x, const int* __restrict__ batch,
    const int* __restrict__ starts, const int* __restrict__ gsize,
    const float* __restrict__ invden,
    const float* __restrict__ W_pos, const float* __restrict__ b_pos,
    unsigned short* __restrict__ h0, int N){
  int n = blockIdx.x * 4 + (threadIdx.x >> 6);
  if (n >= N) return;
  int t = threadIdx.x & 63;
  unsigned short* hrow = h0 + (size_t)n * ENH_PAD;
  if (t < 32){
    const float4* xs = (const float4*)(x + (size_t)n * 128);
    float4 v = xs[t];
    ushort4 o; o.x = f2bf(v.x); o.y = f2bf(v.y); o.z = f2bf(v.z); o.w = f2bf(v.w);
    ((ushort4*)hrow)[t] = o;
  } else if (t < 48){
    int k = t - 32;
    int b = batch[n];
    int i = n - starts[b];
    int g = gsize[b];
    int row = i / g;
    int col = i - row * g;
    float idn = invden[b];
    float pe = (float)row * idn * W_pos[k] + (float)col * idn * W_pos[POSD + k] + b_pos[k];
    hrow[128 + k] = f2bf(pe);
  } else {
    hrow[144 + (t - 48)] = 0;     // zero pad cols 144..159
  }
}

// ---- pack both weights: W [K x 256] fp32 -> Wt [256 x Kp] bf16 --------------
__global__ void k_pack_both(const float* __restrict__ W1, const float* __restrict__ W2,
                            unsigned short* __restrict__ W1t, unsigned short* __restrict__ W2t){
  int idx = blockIdx.x * 256 + threadIdx.x;
  const int n1 = 256 * ENH_PAD;
  if (idx < n1){
    int n = idx / ENH_PAD, k = idx - n * ENH_PAD;
    W1t[idx] = f2bf((k < 144) ? W1[(size_t)k * 256 + n] : 0.f);
  } else {
    int j = idx - n1;
    if (j < 256 * 256){
      int n = j >> 8, k = j & 255;
      W2t[j] = f2bf(W2[(size_t)k * 256 + n]);
    }
  }
}

// ---- bf16 MFMA GEMM + fused attention logits --------------------------------
#define LDST 40   // LDS row stride in bf16 (2-way bank aliasing, free)
__global__ __launch_bounds__(256) void k_mfma_gemm(
    const unsigned short* __restrict__ A, const unsigned short* __restrict__ Bt,
    unsigned short* __restrict__ C,
    const float* __restrict__ a_src, const float* __restrict__ a_dst,
    float* __restrict__ alpS, float* __restrict__ alpD, int M, int Kp){
  __shared__ unsigned short As[128 * LDST];
  __shared__ unsigned short Bs[128 * LDST];
  int t = threadIdx.x;
  int lane = t & 63, wave = t >> 6;
  int wm = (wave >> 1) * 64, wn = (wave & 1) * 64;
  int quad = lane >> 4, l16 = lane & 15;
  int row0 = blockIdx.x * 128;
  int n0 = blockIdx.y * 128;

  f32x4 acc[4][4] = {};

  int eA0 = t, eA1 = t + 256;
  for (int kk = 0; kk < Kp; kk += 32){
    #pragma unroll
    for (int rep = 0; rep < 2; ++rep){
      int e = rep ? eA1 : eA0;
      int r = e >> 2, s = e & 3;
      int grow = row0 + r;
      uint4 va = make_uint4(0, 0, 0, 0);
      if (grow < M) va = *(const uint4*)(A + (size_t)grow * Kp + kk + s * 8);
      *(uint4*)&As[r * LDST + s * 8] = va;
      uint4 vb = *(const uint4*)(Bt + (size_t)(n0 + r) * Kp + kk + s * 8);
      *(uint4*)&Bs[r * LDST + s * 8] = vb;
    }
    __syncthreads();
    bf16x8 af[4], bfr[4];
    #pragma unroll
    for (int i = 0; i < 4; ++i)
      af[i] = *(const bf16x8*)&As[(wm + i * 16 + l16) * LDST + quad * 8];
    #pragma unroll
    for (int j = 0; j < 4; ++j)
      bfr[j] = *(const bf16x8*)&Bs[(wn + j * 16 + l16) * LDST + quad * 8];
    #pragma unroll
    for (int i = 0; i < 4; ++i)
      #pragma unroll
      for (int j = 0; j < 4; ++j)
        acc[i][j] = __builtin_amdgcn_mfma_f32_16x16x32_bf16(af[i], bfr[j], acc[i][j], 0, 0, 0);
    __syncthreads();
  }
  // C store: C/D layout col=lane&15, row=quad*4+reg
  #pragma unroll
  for (int i = 0; i < 4; ++i){
    int rbase = row0 + wm + i * 16 + quad * 4;
    #pragma unroll
    for (int j = 0; j < 4; ++j){
      int col = n0 + wn + j * 16 + l16;
      #pragma unroll
      for (int r = 0; r < 4; ++r){
        int row = rbase + r;
        if (row < M) C[(size_t)row * 256 + col] = f2bf(acc[i][j][r]);
      }
    }
  }
  // fused alphas: this wave's columns n0+wn..+63 == head hda
  int hda = (n0 + wn) >> 6;
  float asw[4], adw[4];
  #pragma unroll
  for (int j = 0; j < 4; ++j){
    int c = n0 + wn + j * 16 + l16;
    asw[j] = a_src[c];
    adw[j] = a_dst[c];
  }
  #pragma unroll
  for (int i = 0; i < 4; ++i){
    #pragma unroll
    for (int r = 0; r < 4; ++r){
      int row = row0 + wm + i * 16 + quad * 4 + r;
      float ps = acc[i][0][r] * asw[0] + acc[i][1][r] * asw[1]
               + acc[i][2][r] * asw[2] + acc[i][3][r] * asw[3];
      float pd = acc[i][0][r] * adw[0] + acc[i][1][r] * adw[1]
               + acc[i][2][r] * adw[2] + acc[i][3][r] * adw[3];
      ps += __shfl_xor(ps, 1); ps += __shfl_xor(ps, 2);
      ps += __shfl_xor(ps, 4); ps += __shfl_xor(ps, 8);
      pd += __shfl_xor(pd, 1); pd += __shfl_xor(pd, 2);
      pd += __shfl_xor(pd, 4); pd += __shfl_xor(pd, 8);
      if (l16 == 0 && row < M){
        alpS[row * 4 + hda] = ps;
        alpD[row * 4 + hda] = pd;
      }
    }
  }
}

// ---- parallel scan of indeg -> row_ptr / cursor -----------------------------
__device__ __forceinline__ int block_excl_scan_256(int val, int* lds){
  int t = threadIdx.x;
  int lane = t & 63, w = t >> 6;
  int incl = val;
  #pragma unroll
  for (int off = 1; off < 64; off <<= 1){
    int v = __shfl_up(incl, off);
    if (lane >= off) incl += v;
  }
  if (lane == 63) lds[w] = incl;
  __syncthreads();
  int wofs = 0;
  #pragma unroll
  for (int i = 0; i < 4; ++i) if (i < w) wofs += lds[i];
  return wofs + incl - val;
}

__global__ __launch_bounds__(256) void k_scan1(const int* __restrict__ indeg,
                                               int* __restrict__ bsums, int N){
  int i = blockIdx.x * 256 + threadIdx.x;
  int v = (i < N) ? indeg[i] : 0;
  int s = v;
  #pragma unroll
  for (int off = 32; off; off >>= 1) s += __shfl_xor(s, off);
  __shared__ int wt[4];
  if ((threadIdx.x & 63) == 0) wt[threadIdx.x >> 6] = s;
  __syncthreads();
  if (threadIdx.x == 0) bsums[blockIdx.x] = wt[0] + wt[1] + wt[2] + wt[3];
}

__global__ __launch_bounds__(1024) void k_scan2_meta(const int* __restrict__ bsums,
                                                     int* __restrict__ boffs,
                                                     int* __restrict__ row_ptr,
                                                     const int* __restrict__ starts,
                                                     int* __restrict__ gsize,
                                                     float* __restrict__ invden,
                                                     float* __restrict__ invcnt,
                                                     int NB, int N){
  int t = threadIdx.x;
  if (t < 64){
    int c = starts[t + 1] - starts[t];
    int g = (int)ceilf(sqrtf((float)c));
    gsize[t] = g;
    int dd = g - 1; if (dd < 1) dd = 1;
    invden[t] = 1.0f / (float)dd;
    invcnt[t] = (c > 0) ? 1.0f / (float)c : 0.0f;
  }
  int v = (t < NB) ? bsums[t] : 0;
  int lane = t & 63, w = t >> 6;
  int incl = v;
  #pragma unroll
  for (int off = 1; off < 64; off <<= 1){
    int x = __shfl_up(incl, off);
    if (lane >= off) incl += x;
  }
  __shared__ int wt[16];
  if (lane == 63) wt[w] = incl;
  __syncthreads();
  int wofs = 0;
  for (int i = 0; i < w; ++i) wofs += wt[i];
  if (t < NB) boffs[t] = wofs + incl - v;
  if (t == 1023){
    int tot = 0;
    for (int i = 0; i < 16; ++i) tot += wt[i];
    row_ptr[N] = tot;
  }
}

__global__ __launch_bounds__(256) void k_scan3(const int* __restrict__ indeg,
                                               const int* __restrict__ boffs,
                                               int* __restrict__ row_ptr,
                                               int* __restrict__ cursor, int N){
  __shared__ int lds[4];
  int i = blockIdx.x * 256 + threadIdx.x;
  int v = (i < N) ? indeg[i] : 0;
  int ex = block_excl_scan_256(v, lds) + boffs[blockIdx.x];
  if (i < N){
    row_ptr[i] = ex;
    cursor[i] = ex;
  }
}

__global__ void k_scatter(const int* __restrict__ src, const int* __restrict__ dst,
                          int* cursor, int* __restrict__ csr_src, int E){
  int e = blockIdx.x * blockDim.x + threadIdx.x;
  if (e < E){
    int slot = atomicAdd(&cursor[dst[e]], 1);
    csr_src[slot] = src[e];
  }
}

// ---- GAT aggregation (R9 form — measured best): one wave/node, 4 heads,
//      batched gathers; full-16 chunks + 4-granular tail. --------------------
__global__ __launch_bounds__(256) void k_aggregate(const unsigned short* __restrict__ hlin,
                                                   const float* __restrict__ alpS,
                                                   const float* __restrict__ alpD,
                                                   const int* __restrict__ row_ptr,
                                                   const int* __restrict__ csr_src,
                                                   const float* __restrict__ bias,
                                                   unsigned short* __restrict__ outb, int N){
  int n = blockIdx.x * 4 + (threadIdx.x >> 6);
  if (n >= N) return;
  int lane = threadIdx.x & 63;
  int hd = lane >> 4;          // channel-domain head
  int hd2 = lane & 3;          // score-domain head
  int eloc = lane >> 2;        // score-domain edge slot 0..15
  int beg = row_ptr[n];
  int deg = row_ptr[n + 1] - beg;
  int total = deg + 1;         // + implicit self-loop
  float ad2 = alpD[n * 4 + hd2];
  float lsum = 0.f;
  float a0 = 0.f, a1 = 0.f, a2 = 0.f, a3 = 0.f;
  const unsigned short* hbase = hlin + (size_t)lane * 4;

  int full = total & ~15;
  for (int base = 0; base < full; base += 16){
    int e = base + eloc;                    // always < total
    int s = (e < deg) ? csr_src[beg + e] : n;
    float xv = alpS[s * 4 + hd2] + ad2;
    float sc = (xv >= 0.f) ? xv : 0.2f * xv;
    float p = __expf(sc);
    lsum += p;
    uint2 v[16];
    #pragma unroll
    for (int j2 = 0; j2 < 16; ++j2){
      int sj = __shfl(s, j2 << 2);
      v[j2] = *(const uint2*)(hbase + (size_t)sj * 256);
    }
    #pragma unroll
    for (int j2 = 0; j2 < 16; ++j2){
      float pj = __shfl(p, (j2 << 2) | hd);
      a0 += pj * __uint_as_float(v[j2].x << 16);
      a1 += pj * __uint_as_float(v[j2].x & 0xFFFF0000u);
      a2 += pj * __uint_as_float(v[j2].y << 16);
      a3 += pj * __uint_as_float(v[j2].y & 0xFFFF0000u);
    }
  }
  int rem = total - full;                   // 0..15
  if (rem){
    int e = full + eloc;
    int s = n;
    float p = 0.f;
    if (eloc < rem){
      if (e < deg) s = csr_src[beg + e];
      float xv = alpS[s * 4 + hd2] + ad2;
      float sc = (xv >= 0.f) ? xv : 0.2f * xv;
      p = __expf(sc);
    }
    lsum += p;
    #pragma unroll
    for (int g = 0; g < 4; ++g){
      if (g * 4 < rem){                     // wave-uniform branch
        uint2 v[4];
        #pragma unroll
        for (int q = 0; q < 4; ++q){
          int j2 = g * 4 + q;
          int sj = __shfl(s, j2 << 2);
          v[q] = *(const uint2*)(hbase + (size_t)sj * 256);
        }
        #pragma unroll
        for (int q = 0; q < 4; ++q){
          int j2 = g * 4 + q;
          float pj = __shfl(p, (j2 << 2) | hd);
          a0 += pj * __uint_as_float(v[q].x << 16);
          a1 += pj * __uint_as_float(v[q].x & 0xFFFF0000u);
          a2 += pj * __uint_as_float(v[q].y << 16);
          a3 += pj * __uint_as_float(v[q].y & 0xFFFF0000u);
        }
      }
    }
  }
  lsum += __shfl_xor(lsum, 4);
  lsum += __shfl_xor(lsum, 8);
  lsum += __shfl_xor(lsum, 16);
  lsum += __shfl_xor(lsum, 32);
  float lh = __shfl(lsum, hd);
  float inv = 1.0f / lh;
  float4 bv = *(const float4*)(bias + lane * 4);
  ushort4 o;
  o.x = f2bf(a0 * inv + bv.x);
  o.y = f2bf(a1 * inv + bv.y);
  o.z = f2bf(a2 * inv + bv.z);
  o.w = f2bf(a3 * inv + bv.w);
  *(ushort4*)(outb + (size_t)n * 256 + lane * 4) = o;
}

// ---- BatchNorm stats (bf16 input) -------------------------------------------
__global__ __launch_bounds__(256) void k_bn_stats(const unsigned short* __restrict__ in,
                                                  float* __restrict__ sums,
                                                  float* __restrict__ sqs, int N){
  int t = threadIdx.x;
  int nb = gridDim.x;
  int rows = (N + nb - 1) / nb;
  int r0 = blockIdx.x * rows, r1 = min(r0 + rows, N);
  float s = 0.f, q = 0.f;
  for (int r = r0; r < r1; ++r){
    float v = bf2f(in[(size_t)r * 256 + t]);
    s += v; q += v * v;
  }
  atomicAdd(&sums[t], s);
  atomicAdd(&sqs[t], q);
}

// ---- BN apply + ELU (bf16 in -> bf16 out, layer 1), uint4-vectorized --------
__global__ __launch_bounds__(256) void k_bn_elu_bf16(
    const unsigned short* __restrict__ in, const float* __restrict__ sums,
    const float* __restrict__ sqs, const float* __restrict__ gamma,
    const float* __restrict__ beta, unsigned short* __restrict__ outb,
    int N, float invN){
  int idx8 = blockIdx.x * blockDim.x + threadIdx.x;   // unit = 8 bf16
  int total8 = N * 32;
  for (; idx8 < total8; idx8 += gridDim.x * blockDim.x){
    int c0 = (idx8 * 8) & 255;
    uint4 raw = *(const uint4*)(in + (size_t)idx8 * 8);
    unsigned int rw[4] = {raw.x, raw.y, raw.z, raw.w};
    uint4 outw;
    unsigned int* ow = (unsigned int*)&outw;
    #pragma unroll
    for (int h = 0; h < 4; ++h){
      unsigned int res = 0;
      #pragma unroll
      for (int k = 0; k < 2; ++k){
        int c = c0 + h * 2 + k;
        float mean = sums[c] * invN;
        float var = sqs[c] * invN - mean * mean;
        float inv = rsqrtf(var + 1e-5f);
        unsigned short bits = (unsigned short)((rw[h] >> (16 * k)) & 0xFFFF);
        float y = gamma[c] * (bf2f(bits) - mean) * inv + beta[c];
        y = (y > 0.f) ? y : (__expf(y) - 1.f);
        res |= ((unsigned int)f2bf(y)) << (16 * k);
      }
      ow[h] = res;
    }
    *(uint4*)(outb + (size_t)idx8 * 8) = outw;
  }
}

// ---- BN apply + ELU + mean-pool partials (bf16 in, layer 2) -----------------
__global__ __launch_bounds__(256) void k_bn_elu_pool(
    const unsigned short* __restrict__ in, const float* __restrict__ sums,
    const float* __restrict__ sqs, const float* __restrict__ gamma,
    const float* __restrict__ beta, const int* __restrict__ batch,
    float* __restrict__ pooled, int N, float invN){
  int t = threadIdx.x;
  float mean = sums[t] * invN;
  float var = sqs[t] * invN - mean * mean;
  float inv = rsqrtf(var + 1e-5f);
  float g = gamma[t], be = beta[t];
  int nb = gridDim.x;
  int rows = (N + nb - 1) / nb;
  int r0 = blockIdx.x * rows, r1 = min(r0 + rows, N);
  float acc = 0.f; int cur = -1;
  for (int r = r0; r < r1; ++r){
    float y = g * (bf2f(in[(size_t)r * 256 + t]) - mean) * inv + be;
    y = (y > 0.f) ? y : (__expf(y) - 1.f);
    int b = batch[r];
    if (b != cur){
      if (cur >= 0) atomicAdd(&pooled[cur * 256 + t], acc);
      acc = 0.f; cur = b;
    }
    acc += y;
  }
  if (cur >= 0) atomicAdd(&pooled[cur * 256 + t], acc);
}

// ---- final FC ---------------------------------------------------------------
__global__ __launch_bounds__(128) void k_final(const float* __restrict__ pooled,
                                               const float* __restrict__ invcnt,
                                               const float* __restrict__ W_fc,
                                               const float* __restrict__ b_fc,
                                               float* __restrict__ out){
  __shared__ float pm[256];
  int b = blockIdx.x;
  int t = threadIdx.x;            // 128
  float ic = invcnt[b];
  pm[t] = pooled[b * 256 + t] * ic;
  pm[t + 128] = pooled[b * 256 + t + 128] * ic;
  __syncthreads();
  float acc = b_fc[t];
  #pragma unroll 4
  for (int c = 0; c < 256; ++c) acc += pm[c] * W_fc[c * 128 + t];
  out[b * 128 + t] = acc;
}

extern "C" void kernel_launch(void* const* d_in, const int* in_sizes, int n_in,
                              void* d_out, int out_size, void* d_ws, size_t ws_size,
                              hipStream_t stream){
  const float* x      = (const float*)d_in[0];
  const int*   eidx   = (const int*)  d_in[1];
  const int*   batch  = (const int*)  d_in[2];
  const float* W_pos  = (const float*)d_in[3];
  const float* b_pos  = (const float*)d_in[4];
  const float* W1     = (const float*)d_in[5];
  const float* a_src1 = (const float*)d_in[6];
  const float* a_dst1 = (const float*)d_in[7];
  const float* b1     = (const float*)d_in[8];
  const float* gamma1 = (const float*)d_in[9];
  const float* beta1  = (const float*)d_in[10];
  const float* W2     = (const float*)d_in[11];
  const float* a_src2 = (const float*)d_in[12];
  const float* a_dst2 = (const float*)d_in[13];
  const float* b2     = (const float*)d_in[14];
  const float* gamma2 = (const float*)d_in[15];
  const float* beta2  = (const float*)d_in[16];
  const float* W_fc   = (const float*)d_in[17];
  const float* b_fc   = (const float*)d_in[18];
  float* out = (float*)d_out;

  const int N = in_sizes[0] / 128;
  const int E = in_sizes[1] / 2;
  const int* esrc = eidx;
  const int* edst = eidx + E;

  char* w = (char*)d_ws;
  size_t off = 0;
  auto alloc = [&](size_t bytes) -> void* {
    void* p = w + off;
    off = (off + bytes + 255) & ~(size_t)255;
    return p;
  };
  unsigned short* h0   = (unsigned short*)alloc((size_t)N * 256 * 2);
  unsigned short* X2b  = h0;      // reused: disjoint lifetimes (h0 dead after GEMM1)
  unsigned short* X1b  = (unsigned short*)alloc((size_t)N * 256 * 2);  // GEMM out
  unsigned short* A1b  = (unsigned short*)alloc((size_t)N * 256 * 2);  // aggregate out
  float* alpS    = (float*)alloc((size_t)N * 4 * 4);
  float* alpD    = (float*)alloc((size_t)N * 4 * 4);
  int*   starts  = (int*)  alloc(65 * 4);
  int*   gsize   = (int*)  alloc(64 * 4);
  float* invden  = (float*)alloc(64 * 4);
  float* invcnt  = (float*)alloc(64 * 4);
  int*   indeg   = (int*)  alloc((size_t)N * 4);
  int*   row_ptr = (int*)  alloc((size_t)(N + 1) * 4);
  int*   cursor  = (int*)  alloc((size_t)(N + 1) * 4);
  int*   csr_src = (int*)  alloc((size_t)E * 4);
  int*   bsums   = (int*)  alloc(1024 * 4);
  int*   boffs   = (int*)  alloc(1024 * 4);
  float* bnstats = (float*)alloc(4 * 256 * 4);   // S1 | Q1 | S2 | Q2
  float* pooled  = (float*)alloc(64 * 256 * 4);
  unsigned short* W1t = (unsigned short*)alloc(256 * ENH_PAD * 2);
  unsigned short* W2t = (unsigned short*)alloc(256 * 256 * 2);
  float* bnS1 = bnstats, *bnQ1 = bnstats + 256, *bnS2 = bnstats + 512, *bnQ2 = bnstats + 768;

  hipMemsetAsync(indeg, 0, (size_t)N * 4, stream);

  const int NB = (N + 255) / 256;
  int nb4 = (N + 3) / 4;

  // front-end: starts + indeg + zero stats/pooled, then scan + scatter
  k_front<<<(E + 255) / 256, 256, 0, stream>>>(batch, starts, edst, indeg,
                                               bnstats, pooled, N, E);
  k_scan1<<<NB, 256, 0, stream>>>(indeg, bsums, N);
  k_scan2_meta<<<1, 1024, 0, stream>>>(bsums, boffs, row_ptr, starts,
                                       gsize, invden, invcnt, NB, N);
  k_scan3<<<NB, 256, 0, stream>>>(indeg, boffs, row_ptr, cursor, N);
  k_scatter<<<(E + 255) / 256, 256, 0, stream>>>(esrc, edst, cursor, csr_src, E);

  k_build_h0<<<nb4, 256, 0, stream>>>(x, batch, starts, gsize, invden, W_pos, b_pos, h0, N);
  k_pack_both<<<(256 * ENH_PAD + 256 * 256 + 255) / 256, 256, 0, stream>>>(W1, W2, W1t, W2t);

  dim3 ggrid((N + 127) / 128, 2);

  // layer 1
  k_mfma_gemm<<<ggrid, 256, 0, stream>>>(h0, W1t, X1b, a_src1, a_dst1, alpS, alpD, N, ENH_PAD);
  k_aggregate<<<nb4, 256, 0, stream>>>(X1b, alpS, alpD, row_ptr, csr_src, b1, A1b, N);
  k_bn_stats<<<512, 256, 0, stream>>>(A1b, bnS1, bnQ1, N);
  k_bn_elu_bf16<<<3200, 256, 0, stream>>>(A1b, bnS1, bnQ1, gamma1, beta1, X2b, N, 1.0f / (float)N);

  // layer 2
  k_mfma_gemm<<<ggrid, 256, 0, stream>>>(X2b, W2t, X1b, a_src2, a_dst2, alpS, alpD, N, 256);
  k_aggregate<<<nb4, 256, 0, stream>>>(X1b, alpS, alpD, row_ptr, csr_src, b2, A1b, N);
  k_bn_stats<<<512, 256, 0, stream>>>(A1b, bnS2, bnQ2, N);
  k_bn_elu_pool<<<512, 256, 0, stream>>>(A1b, bnS2, bnQ2, gamma2, beta2, batch,
                                         pooled, N, 1.0f / (float)N);

  // fc
  k_final<<<64, 128, 0, stream>>>(pooled, invcnt, W_fc, b_fc, out);
}